// Round 15
// baseline (1314.117 us; speedup 1.0000x reference)
//
#include <hip/hip_runtime.h>
#include <math.h>

#define T_  6
#define N_  50000
#define NH_ 128
#define R_  2
#define E_  800000
#define SEMW_BLOCKS ((2*N_ + 127)/128)   // 782
#define NCHUNK 49                         // ceil(N/1024)

typedef __attribute__((ext_vector_type(8))) short bf16x8;
typedef __attribute__((ext_vector_type(4))) float f32x4;

__device__ inline unsigned short f2b(float f) {
    union { float f; unsigned int u; } v; v.f = f;
    unsigned int u = v.u;
    unsigned int r = (u + 0x7FFFu + ((u >> 16) & 1u)) >> 16;
    return (unsigned short)r;
}
__device__ inline float b2f(unsigned short h) {
    union { unsigned int u; float f; } v; v.u = ((unsigned int)h) << 16;
    return v.f;
}
// async 16B global->LDS (linear LDS dest = wave-uniform base + lane*16)
__device__ inline void gload16(const void* g, void* l) {
    __builtin_amdgcn_global_load_lds((const __attribute__((address_space(1))) void*)g,
                                     (__attribute__((address_space(3))) void*)l, 16, 0, 0);
}

// ---------------------------------------------------------------- CSR build
__global__ void hist_kernel(const int* __restrict__ dst, int* __restrict__ counts) {
    int j = blockIdx.x * blockDim.x + threadIdx.x;
    if (j < R_ * E_) atomicAdd(&counts[(j / E_) * N_ + dst[j]], 1);
}

__global__ __launch_bounds__(1024) void scan1_kernel(const int* __restrict__ counts,
                                                     int* __restrict__ lexcl,
                                                     int* __restrict__ csums) {
    int r = blockIdx.y, c = blockIdx.x;
    int i = c * 1024 + threadIdx.x;
    int v = (i < N_) ? counts[r * N_ + i] : 0;
    __shared__ int sm[1024];
    sm[threadIdx.x] = v;
    __syncthreads();
    for (int off = 1; off < 1024; off <<= 1) {
        int t = 0;
        if (threadIdx.x >= off) t = sm[threadIdx.x - off];
        __syncthreads();
        sm[threadIdx.x] += t;
        __syncthreads();
    }
    if (i < N_) lexcl[r * N_ + i] = sm[threadIdx.x] - v;
    if (threadIdx.x == 1023) csums[r * 64 + c] = sm[1023];
}

__global__ void scan2_kernel(int* __restrict__ csums, int* __restrict__ offsets) {
    int r = threadIdx.x >> 6, l = threadIdx.x & 63;
    if (r < R_) {
        int v = (l < NCHUNK) ? csums[r * 64 + l] : 0;
        int s = v;
        for (int off = 1; off < 64; off <<= 1) {
            int t = __shfl_up(s, off);
            if (l >= off) s += t;
        }
        if (l < NCHUNK) csums[r * 64 + l] = s - v;
        if (l == NCHUNK - 1) offsets[r * (N_ + 1) + N_] = s;
    }
}

__global__ __launch_bounds__(1024) void scan3_kernel(const int* __restrict__ lexcl,
                                                     const int* __restrict__ csums,
                                                     int* __restrict__ offsets,
                                                     int* __restrict__ cursor) {
    int r = blockIdx.y;
    int i = blockIdx.x * 1024 + threadIdx.x;
    if (i < N_) {
        int o = lexcl[r * N_ + i] + csums[r * 64 + blockIdx.x];
        offsets[r * (N_ + 1) + i] = o;
        cursor[r * N_ + i] = o;
    }
}

__global__ void scatter_kernel(const int* __restrict__ src, const int* __restrict__ dst,
                               int* __restrict__ cursor, int* __restrict__ srcs_sorted) {
    int j = blockIdx.x * blockDim.x + threadIdx.x;
    if (j < R_ * E_) {
        int r = j / E_;
        int pos = atomicAdd(&cursor[r * N_ + dst[j]], 1);
        srcs_sorted[(size_t)r * E_ + pos] = src[j] << 8;   // prescaled byte offset (256 B/row)
    }
}

// ---------------------------------------------------------------- small precomputes
__global__ void pe_kernel(float* __restrict__ pe) {
    int c = threadIdx.x;
    int k = c & ~1;
    double div = exp((double)k * (-log(100000.0) / 128.0));
    for (int t = 0; t < T_; t++) {
        double pos = (double)(t + 1);
        double v = (c & 1) ? cos(pos * div) : sin(pos * div);
        pe[t * NH_ + c] = (float)v;
    }
}

struct CvtArgs {
    const float* s[6];
    unsigned short* d[6];
};
__global__ void cvt_wt_kernel(CvtArgs a) {
    int y = blockIdx.y, n = blockIdx.x, k = threadIdx.x;
    a.d[y][n * 128 + k] = f2b(a.s[y][k * 128 + n]);
}

__global__ void build_m_kernel(const float* __restrict__ qw, const float* __restrict__ kw,
                               const float* __restrict__ vw, const float* __restrict__ fcw,
                               float* __restrict__ Mu, float* __restrict__ Mwv) {
    int y = blockIdx.y, c = blockIdx.x, f = threadIdx.x;
    float s = 0.f;
    if (y == 0) {
        for (int d = 0; d < 128; d++) s += kw[f * 128 + d] * qw[c * 128 + d];
        Mu[c * 128 + f] = s;
    } else {
        for (int d = 0; d < 128; d++) s += vw[f * 128 + d] * fcw[d * 128 + c];
        Mwv[c * 128 + f] = s;
    }
}

__global__ void fold_w_kernel(const float* __restrict__ proj, const float* __restrict__ Mu,
                              const float* __restrict__ Mwv, unsigned short* __restrict__ wt_hh,
                              unsigned short* __restrict__ wt_pu, unsigned short* __restrict__ wt_pwv) {
    int y = blockIdx.y, c = blockIdx.x, k = threadIdx.x;
    if (y == 0) { wt_hh[c * 128 + k] = f2b(proj[k * 128 + c]); return; }
    const float* M = (y == 1) ? Mu : Mwv;
    float s = 0.f;
    for (int f = 0; f < 128; f++) s += proj[k * 128 + f] * M[c * 128 + f];
    ((y == 1) ? wt_pu : wt_pwv)[c * 128 + k] = f2b(s);
}

__global__ void fold_c_kernel(const float* __restrict__ proj_b, const float* __restrict__ pe,
                              const float* __restrict__ Mu, const float* __restrict__ Mwv,
                              const float* __restrict__ res_b, float* __restrict__ cbuf) {
    int t = blockIdx.x, c = threadIdx.x;
    cbuf[0 * 768 + t * 128 + c] = proj_b[c] + pe[t * 128 + c];
    float s1 = 0.f, s2 = 0.f;
    for (int f = 0; f < 128; f++) {
        float b = proj_b[f] + pe[t * 128 + f];
        s1 += b * Mu[c * 128 + f];
        s2 += b * Mwv[c * 128 + f];
    }
    cbuf[1 * 768 + t * 128 + c] = s1;
    cbuf[2 * 768 + t * 128 + c] = s2;
    cbuf[3 * 768 + t * 128 + c] = res_b[c];
}

// ---------------------------------------------------------------- MFMA GEMM, 4 fused outputs sharing the staged A-tile
struct MArgs {
    const void* A;               // EPI0: f32 rows; EPI3 mix=0: bf16 rows; EPI3 mix=1: hbuf [t][n][256]
    const void* Axb;             // EPI3 y3: x (f32) in [t][n] layout (mode-1 addressing)
    const unsigned short* W0; const unsigned short* W1;
    const unsigned short* W2; const unsigned short* W3;
    unsigned short* C0; unsigned short* C1; unsigned short* C2; unsigned short* C3;
    const float* cb;             // [4][6][128] (EPI 3)
    const float* beta2;          // [6][2] (mix)
    const float* hb;             // h_bias[128] (mix)
    long row0;
    int  M;
    int  mix;                    // EPI3: 1 = inline beta-mix from hbuf
};

// EPI: 0 = bf16 out, A is f32 (inline convert); 3 = + cb[y][t6][col], y3 reads f32 Axb
template <int EPI>
__global__ __launch_bounds__(256) void mgemm_kernel(MArgs g) {
    __shared__ __align__(16) char As[128 * 256];
    __shared__ __align__(16) char Bs[128 * 256];
    int tid = threadIdx.x;
    int lane = tid & 63;
    int wbase = tid & ~63;               // wave-uniform
    int brow0 = blockIdx.x * 128;
    const unsigned short* Ws[4] = {g.W0, g.W1, g.W2, g.W3};
    unsigned short* Cs[4] = {g.C0, g.C1, g.C2, g.C3};

    auto stageAsync = [&](const char* Sbase, char* L, bool clampRows) {
        int Mm1 = g.M - 1;
#pragma unroll
        for (int i = 0; i < 8; i++) {
            int c0 = wbase + i * 256;
            int cl = c0 + lane;
            int row = cl >> 4;
            int sb = ((cl & 15) << 4) ^ ((row & 7) << 4);
            long srow = clampRows ? (long)min(brow0 + row, Mm1) : (long)row;
            gload16(Sbase + srow * 256 + sb, L + (size_t)c0 * 16);
        }
    };
    auto stageA_f32 = [&](const float* Abase, bool m1) {
#pragma unroll
        for (int i = 0; i < 8; i++) {
            int c = tid + i * 256;
            int row = c >> 4;
            int cb = (c & 15) << 4;
            int scb = cb ^ ((row & 7) << 4);
            int grow = brow0 + row;
            uint4 av = make_uint4(0u, 0u, 0u, 0u);
            if (grow < g.M) {
                long ar;
                if (!m1) ar = grow;
                else { long gg = g.row0 + grow; long n = gg / 6, t = gg - n * 6; ar = t * (long)N_ + n; }
                const float* Af = Abase + ar * 128 + (cb >> 1);
                float4 x0 = *(const float4*)Af;
                float4 x1 = *(const float4*)(Af + 4);
                union { unsigned short s[8]; uint4 u; } o;
                o.s[0] = f2b(x0.x); o.s[1] = f2b(x0.y); o.s[2] = f2b(x0.z); o.s[3] = f2b(x0.w);
                o.s[4] = f2b(x1.x); o.s[5] = f2b(x1.y); o.s[6] = f2b(x1.z); o.s[7] = f2b(x1.w);
                av = o.u;
            }
            *(uint4*)(As + row * 256 + scb) = av;
        }
    };
    // EPI3 mix=1: A row g -> n=g/6, t=g%6; z = relu(relu(b0*h0+b1*h1)+h_bias)
    auto stageA_mix = [&](const unsigned short* H) {
#pragma unroll
        for (int i = 0; i < 8; i++) {
            int c = tid + i * 256;
            int row = c >> 4;
            int cb = (c & 15) << 4;
            int scb = cb ^ ((row & 7) << 4);
            int grow = brow0 + row;
            uint4 av = make_uint4(0u, 0u, 0u, 0u);
            if (grow < g.M) {
                long gg = g.row0 + grow;
                long n = gg / 6, t = gg - n * 6;
                const unsigned short* h = H + t * (size_t)N_ * 256 + n * 256 + (cb >> 1);
                uint4 x0 = *(const uint4*)h;
                uint4 x1 = *(const uint4*)(h + 128);
                float b0 = g.beta2[2 * t], b1 = g.beta2[2 * t + 1];
                const unsigned int* p0 = (const unsigned int*)&x0;
                const unsigned int* p1 = (const unsigned int*)&x1;
                int col0 = cb >> 1;
                union { unsigned short s[8]; uint4 u; } o;
#pragma unroll
                for (int j = 0; j < 8; j++) {
                    unsigned short s0 = (j & 1) ? (unsigned short)(p0[j >> 1] >> 16) : (unsigned short)p0[j >> 1];
                    unsigned short s1 = (j & 1) ? (unsigned short)(p1[j >> 1] >> 16) : (unsigned short)p1[j >> 1];
                    float z = fmaxf(fmaxf(b0 * b2f(s0) + b1 * b2f(s1), 0.f) + g.hb[col0 + j], 0.f);
                    o.s[j] = f2b(z);
                }
                av = o.u;
            }
            *(uint4*)(As + row * 256 + scb) = av;
        }
    };

    int w = tid >> 6, l = tid & 63;
    int l15 = l & 15, lg = l >> 4;

    if (EPI == 0) stageA_f32((const float*)g.A, false);
    else if (g.mix) stageA_mix((const unsigned short*)g.A);
    else stageAsync((const char*)g.A, As, true);

    for (int y = 0; y < 4; y++) {
        if (y > 0) __syncthreads();
        if (EPI == 3 && y == 3) stageA_f32((const float*)g.Axb, true);
        stageAsync((const char*)Ws[y], Bs, false);
        __syncthreads();

        f32x4 acc[2][8];
#pragma unroll
        for (int a = 0; a < 2; a++)
#pragma unroll
            for (int b = 0; b < 8; b++) acc[a][b] = (f32x4)(0.f);
#pragma unroll
        for (int ks = 0; ks < 4; ks++) {
            bf16x8 bf[8];
#pragma unroll
            for (int nt = 0; nt < 8; nt++) {
                int rn = nt * 16 + l15;
                int cbyte = (ks * 64 + lg * 16) ^ ((rn & 7) << 4);
                bf[nt] = *(const bf16x8*)(Bs + rn * 256 + cbyte);
            }
#pragma unroll
            for (int mt = 0; mt < 2; mt++) {
                int rm = w * 32 + mt * 16 + l15;
                int cbyte = (ks * 64 + lg * 16) ^ ((rm & 7) << 4);
                bf16x8 af = *(const bf16x8*)(As + rm * 256 + cbyte);
#pragma unroll
                for (int nt = 0; nt < 8; nt++)
                    acc[mt][nt] = __builtin_amdgcn_mfma_f32_16x16x32_bf16(af, bf[nt], acc[mt][nt], 0, 0, 0);
            }
        }
        unsigned short* C = Cs[y];
#pragma unroll
        for (int mt = 0; mt < 2; mt++) {
#pragma unroll
            for (int r = 0; r < 4; r++) {
                int row = w * 32 + mt * 16 + lg * 4 + r;
                int grow = brow0 + row;
                if (grow >= g.M) continue;
                long t6 = 0;
                if (EPI == 3) t6 = (g.row0 + grow) % 6;
#pragma unroll
                for (int nt = 0; nt < 8; nt++) {
                    int col = nt * 16 + l15;
                    float v = acc[mt][nt][r];
                    if (EPI == 3) v += g.cb[y * 768 + t6 * 128 + col];
                    C[(size_t)grow * 128 + col] = f2b(v);
                }
            }
        }
    }
}

// ---------------------------------------------------------------- semantic w partials (batched over t via blockIdx.y)
__global__ __launch_bounds__(256) void semw_kernel(const unsigned short* __restrict__ Abase,
                                                   const unsigned short* __restrict__ Wt,
                                                   const float* __restrict__ b1,
                                                   const float* __restrict__ w2,
                                                   float* __restrict__ partials) {
    __shared__ __align__(16) char As[128 * 256];
    __shared__ __align__(16) char Bs[128 * 256];
    __shared__ float bs[2];
    int tid = threadIdx.x;
    if (tid < 2) bs[tid] = 0.f;
    int lane = tid & 63;
    int wbase = tid & ~63;
    int tl = blockIdx.y;
    const char* A = (const char*)(Abase + (size_t)tl * N_ * 256);
    const int M = 2 * N_;
    int brow0 = blockIdx.x * 128;
#pragma unroll
    for (int i = 0; i < 8; i++) {
        int c0 = wbase + i * 256;
        int cl = c0 + lane;
        int row = cl >> 4;
        int sb = ((cl & 15) << 4) ^ ((row & 7) << 4);
        gload16((const char*)Wt + (long)row * 256 + sb, Bs + (size_t)c0 * 16);
        long srow = min(brow0 + row, M - 1);
        gload16(A + srow * 256 + sb, As + (size_t)c0 * 16);
    }
    __syncthreads();
    int w = tid >> 6, l = tid & 63;
    int l15 = l & 15, lg = l >> 4;
    f32x4 acc[2][8];
#pragma unroll
    for (int a = 0; a < 2; a++)
#pragma unroll
        for (int b = 0; b < 8; b++) acc[a][b] = (f32x4)(0.f);
#pragma unroll
    for (int ks = 0; ks < 4; ks++) {
        bf16x8 bf[8];
#pragma unroll
        for (int nt = 0; nt < 8; nt++) {
            int rn = nt * 16 + l15;
            int cbyte = (ks * 64 + lg * 16) ^ ((rn & 7) << 4);
            bf[nt] = *(const bf16x8*)(Bs + rn * 256 + cbyte);
        }
#pragma unroll
        for (int mt = 0; mt < 2; mt++) {
            int rm = w * 32 + mt * 16 + l15;
            int cbyte = (ks * 64 + lg * 16) ^ ((rm & 7) << 4);
            bf16x8 af = *(const bf16x8*)(As + rm * 256 + cbyte);
#pragma unroll
            for (int nt = 0; nt < 8; nt++)
                acc[mt][nt] = __builtin_amdgcn_mfma_f32_16x16x32_bf16(af, bf[nt], acc[mt][nt], 0, 0, 0);
        }
    }
#pragma unroll
    for (int mt = 0; mt < 2; mt++) {
#pragma unroll
        for (int r = 0; r < 4; r++) {
            int row = w * 32 + mt * 16 + lg * 4 + r;
            int grow = brow0 + row;
            float s = 0.f;
#pragma unroll
            for (int nt = 0; nt < 8; nt++) {
                int col = nt * 16 + l15;
                s += tanhf(acc[mt][nt][r] + b1[col]) * w2[col];
            }
#pragma unroll
            for (int mask = 1; mask <= 8; mask <<= 1) s += __shfl_xor(s, mask);
            if (l15 == 0 && grow < M) atomicAdd(&bs[grow & 1], s);
        }
    }
    __syncthreads();
    if (tid < 2) partials[((size_t)tl * SEMW_BLOCKS + blockIdx.x) * 2 + tid] = bs[tid];
}

__global__ __launch_bounds__(512) void beta_kernel(const float* __restrict__ partials,
                                                   float* __restrict__ beta2) {
    int t = blockIdx.x;
    const float* p = partials + (size_t)t * SEMW_BLOCKS * 2;
    float s0 = 0.f, s1 = 0.f;
    for (int i = threadIdx.x; i < SEMW_BLOCKS; i += 512) { s0 += p[i * 2]; s1 += p[i * 2 + 1]; }
#pragma unroll
    for (int mask = 1; mask <= 32; mask <<= 1) { s0 += __shfl_xor(s0, mask); s1 += __shfl_xor(s1, mask); }
    __shared__ float w0[8], w1[8];
    int w = threadIdx.x >> 6;
    if ((threadIdx.x & 63) == 0) { w0[w] = s0; w1[w] = s1; }
    __syncthreads();
    if (threadIdx.x == 0) {
        float t0 = 0.f, t1 = 0.f;
        for (int i = 0; i < 8; i++) { t0 += w0[i]; t1 += w1[i]; }
        float m0 = t0 / (float)N_, m1 = t1 / (float)N_;
        float mx = fmaxf(m0, m1);
        float e0 = __expf(m0 - mx), e1 = __expf(m1 - mx);
        float inv = 1.f / (e0 + e1);
        beta2[t * 2] = e0 * inv; beta2[t * 2 + 1] = e1 * inv;
    }
}

// ---------------------------------------------------------------- GAT edge aggregation: 4 nodes/wave, 16 lanes/node, 8 ch/lane
// depth-2 clamped prefetch + exp2-domain scores (av pre-scaled by log2 e)
__global__ __launch_bounds__(256) void gat_edge_kernel(const unsigned short* __restrict__ R0,
                                                       const int* __restrict__ offsets,
                                                       const int* __restrict__ srcs_sorted,
                                                       const float* __restrict__ gat_attn,
                                                       const float* __restrict__ gat_bias,
                                                       unsigned short* __restrict__ hbuf, int TB) {
    int y = blockIdx.x >> 10;              // slice (slow dimension)
    int bid = blockIdx.x & 1023;
    int r = y & 1, tl = y >> 1;
    const char* fsb = (const char*)(R0 + ((size_t)(2 * r) * TB + tl) * N_ * 128);
    const unsigned short* fd = R0 + ((size_t)(2 * r + 1) * TB + tl) * N_ * 128;
    unsigned short* hout = hbuf + (size_t)tl * N_ * 256;
    const int* offs = offsets + r * (N_ + 1);
    const int* srcs = srcs_sorted + (size_t)r * E_;
    int lane = threadIdx.x & 63;
    int q = lane >> 4, l16 = lane & 15;
    int c0 = l16 * 8;
    const char* fsc = fsb + c0 * 2;
    int wid = (bid * blockDim.x + threadIdx.x) >> 6;
    int nw = (1024 * blockDim.x) >> 6;
    const float LG2E = 1.44269504f;
    float4 a0 = *(const float4*)(gat_attn + r * 128 + c0);
    float4 a1 = *(const float4*)(gat_attn + r * 128 + c0 + 4);
    float av[8] = {a0.x * LG2E, a0.y * LG2E, a0.z * LG2E, a0.w * LG2E,
                   a1.x * LG2E, a1.y * LG2E, a1.z * LG2E, a1.w * LG2E};
    float4 bb0 = *(const float4*)(gat_bias + r * 128 + c0);
    float4 bb1 = *(const float4*)(gat_bias + r * 128 + c0 + 4);
    float bv[8] = {bb0.x, bb0.y, bb0.z, bb0.w, bb1.x, bb1.y, bb1.z, bb1.w};

    for (int gidx = wid; gidx < N_ / 4; gidx += nw) {
        int n = gidx * 4 + q;
        uint4 fdp = *(const uint4*)(fd + (size_t)n * 128 + c0);
        const unsigned int* fdu = (const unsigned int*)&fdp;
        float fdv[8];
#pragma unroll
        for (int j = 0; j < 8; j++)
            fdv[j] = (j & 1) ? b2f((unsigned short)(fdu[j >> 1] >> 16)) : b2f((unsigned short)fdu[j >> 1]);
        int e0 = offs[n], e1 = offs[n + 1];
        int deg = e1 - e0;
        int m = deg;
        m = max(m, __shfl_xor(m, 16));
        m = max(m, __shfl_xor(m, 32));
        int last = max(e1 - 1, 0);         // clamped index: always valid, garbage masked by p=0
        float den = 0.f;
        float acc[8];
#pragma unroll
        for (int j = 0; j < 8; j++) acc[j] = 0.f;

        uint4 fp  = *(const uint4*)(fsc + srcs[min(e0, last)]);
        uint4 np1 = *(const uint4*)(fsc + srcs[min(e0 + 1, last)]);
        for (int i = 0; i < m; i++) {
            uint4 np2 = *(const uint4*)(fsc + srcs[min(e0 + i + 2, last)]);
            const unsigned int* fu = (const unsigned int*)&fp;
            float f[8];
            float vlin = 0.f, vabs = 0.f;
#pragma unroll
            for (int j = 0; j < 8; j++) {
                f[j] = (j & 1) ? b2f((unsigned short)(fu[j >> 1] >> 16)) : b2f((unsigned short)fu[j >> 1]);
                float t = f[j] + fdv[j];
                vlin = fmaf(av[j], t, vlin);
                vabs = fmaf(av[j], fabsf(t), vabs);     // abs = free input modifier
            }
            float v = fmaf(0.4f, vabs, 0.6f * vlin);    // combine BEFORE reduce (linear, log2-domain)
            v += __int_as_float(__builtin_amdgcn_ds_swizzle(__float_as_int(v), 0x041F));
            v += __int_as_float(__builtin_amdgcn_ds_swizzle(__float_as_int(v), 0x081F));
            float p = (i < deg) ? exp2f(v) : 0.f;       // v_exp_f32 computes 2^x directly
            den += p;
#pragma unroll
            for (int j = 0; j < 8; j++) acc[j] = fmaf(p, f[j], acc[j]);
            fp = np1; np1 = np2;
        }
        float inv = (deg > 0) ? 1.f / den : 0.f;
        union { unsigned short s[8]; uint4 u; } o;
#pragma unroll
        for (int j = 0; j < 8; j++) o.s[j] = f2b(fmaf(acc[j], inv, bv[j]));
        *(uint4*)(hout + (size_t)(n * 2 + r) * 128 + c0) = o.u;
    }
}

// ---------------------------------------------------------------- hsem (TB=2 fallback only)
__global__ void hsem_kernel(const unsigned short* __restrict__ hbuf, const float* __restrict__ beta2,
                            const float* __restrict__ h_bias, unsigned short* __restrict__ inter,
                            int tbase) {
    int idx = blockIdx.x * blockDim.x + threadIdx.x;
    if (idx >= N_ * 16) return;
    int tl = blockIdx.y;
    int t = tbase + tl;
    const unsigned short* h = hbuf + (size_t)tl * N_ * 256;
    int n = idx >> 4, c8 = (idx & 15) * 8;
    float b0 = beta2[tl * 2], b1 = beta2[tl * 2 + 1];
    uint4 x0 = *(const uint4*)(h + (size_t)n * 256 + c8);
    uint4 x1 = *(const uint4*)(h + (size_t)n * 256 + 128 + c8);
    const unsigned int* p0 = (const unsigned int*)&x0;
    const unsigned int* p1 = (const unsigned int*)&x1;
    float4 hb0 = *(const float4*)(h_bias + c8);
    float4 hb1 = *(const float4*)(h_bias + c8 + 4);
    float hbv[8] = {hb0.x, hb0.y, hb0.z, hb0.w, hb1.x, hb1.y, hb1.z, hb1.w};
    union { unsigned short s[8]; uint4 u; } o;
#pragma unroll
    for (int i = 0; i < 8; i++) {
        unsigned short s0 = (i & 1) ? (unsigned short)(p0[i >> 1] >> 16) : (unsigned short)p0[i >> 1];
        unsigned short s1 = (i & 1) ? (unsigned short)(p1[i >> 1] >> 16) : (unsigned short)p1[i >> 1];
        float z = fmaxf(fmaxf(b0 * b2f(s0) + b1 * b2f(s1), 0.f) + hbv[i], 0.f);
        o.s[i] = f2b(z);
    }
    *(uint4*)(inter + ((size_t)n * 6 + t) * 128 + c8) = o.u;
}

// ---------------------------------------------------------------- temporal attention + gated residual + LN
__global__ __launch_bounds__(256) void temporal_kernel(const unsigned short* __restrict__ hh,
                                                       const unsigned short* __restrict__ uu,
                                                       const unsigned short* __restrict__ wvv,
                                                       const unsigned short* __restrict__ rv,
                                                       const float* __restrict__ fc_b,
                                                       const float* __restrict__ res_alpha,
                                                       const float* __restrict__ ln_g,
                                                       const float* __restrict__ ln_b,
                                                       float* __restrict__ out, long n0, int nNodes) {
    int lane = threadIdx.x & 63;
    int wid = (blockIdx.x * blockDim.x + threadIdx.x) >> 6;
    if (wid >= nNodes) return;
    long n = n0 + wid;
    size_t base = (size_t)wid * 6 * 128 + 2 * lane;
    float h2[6][2], u2[6][2], wv2[6][2], rv2[6][2];
#pragma unroll
    for (int t = 0; t < 6; t++) {
        unsigned int hp = *(const unsigned int*)(hh + base + t * 128);
        h2[t][0] = b2f((unsigned short)hp); h2[t][1] = b2f((unsigned short)(hp >> 16));
        unsigned int up = *(const unsigned int*)(uu + base + t * 128);
        u2[t][0] = b2f((unsigned short)up); u2[t][1] = b2f((unsigned short)(up >> 16));
        unsigned int wp = *(const unsigned int*)(wvv + base + t * 128);
        wv2[t][0] = b2f((unsigned short)wp); wv2[t][1] = b2f((unsigned short)(wp >> 16));
        unsigned int rp = *(const unsigned int*)(rv + base + t * 128);
        rv2[t][0] = b2f((unsigned short)rp); rv2[t][1] = b2f((unsigned short)(rp >> 16));
    }
    float sc[6][6];
#pragma unroll
    for (int t = 0; t < 6; t++)
#pragma unroll
        for (int s = 0; s < 6; s++)
            sc[t][s] = h2[t][0] * u2[s][0] + h2[t][1] * u2[s][1];
#pragma unroll
    for (int mask = 1; mask <= 32; mask <<= 1)
#pragma unroll
        for (int t = 0; t < 6; t++)
#pragma unroll
            for (int s = 0; s < 6; s++)
                sc[t][s] += __shfl_xor(sc[t][s], mask);

    float a = 1.f / (1.f + __expf(-res_alpha[0]));
    float2 fb = ((const float2*)fc_b)[lane];
    float2 lg = ((const float2*)ln_g)[lane];
    float2 lb = ((const float2*)ln_b)[lane];
#pragma unroll
    for (int t = 0; t < 6; t++) {
        float mx = sc[t][0];
#pragma unroll
        for (int s = 1; s < 6; s++) mx = fmaxf(mx, sc[t][s]);
        float p[6]; float den = 0.f;
#pragma unroll
        for (int s = 0; s < 6; s++) { p[s] = __expf(sc[t][s] - mx); den += p[s]; }
        float inv = 1.f / den;
        float ox = 0.f, oy = 0.f;
#pragma unroll
        for (int s = 0; s < 6; s++) { ox += p[s] * wv2[s][0]; oy += p[s] * wv2[s][1]; }
        ox = fmaxf(ox * inv + fb.x, 0.f);
        oy = fmaxf(oy * inv + fb.y, 0.f);
        ox = ox * a + rv2[t][0] * (1.f - a);
        oy = oy * a + rv2[t][1] * (1.f - a);
        float s1 = ox + oy, s2 = ox * ox + oy * oy;
#pragma unroll
        for (int mask = 1; mask <= 32; mask <<= 1) {
            s1 += __shfl_xor(s1, mask);
            s2 += __shfl_xor(s2, mask);
        }
        float mu = s1 * (1.f / 128.f);
        float var = s2 * (1.f / 128.f) - mu * mu;
        float rs = rsqrtf(var + 1e-5f);
        float2 o;
        o.x = (ox - mu) * rs * lg.x + lb.x;
        o.y = (oy - mu) * rs * lg.y + lb.y;
        ((float2*)(out + ((size_t)t * N_ + n) * 128))[lane] = o;
    }
}

// ---------------------------------------------------------------- launch
extern "C" void kernel_launch(void* const* d_in, const int* in_sizes, int n_in,
                              void* d_out, int out_size, void* d_ws, size_t ws_size,
                              hipStream_t stream) {
    const float* x        = (const float*)d_in[0];
    const int*   src      = (const int*)d_in[1];
    const int*   dst      = (const int*)d_in[2];
    const float* gat_wsrc = (const float*)d_in[3];
    const float* gat_wdst = (const float*)d_in[4];
    const float* gat_attn = (const float*)d_in[5];
    const float* gat_bias = (const float*)d_in[6];
    const float* h_bias   = (const float*)d_in[7];
    const float* sem_w1   = (const float*)d_in[8];
    const float* sem_b1   = (const float*)d_in[9];
    const float* sem_w2   = (const float*)d_in[10];
    const float* proj_w   = (const float*)d_in[11];
    const float* proj_b   = (const float*)d_in[12];
    const float* qw       = (const float*)d_in[13];
    const float* kw       = (const float*)d_in[14];
    const float* vw       = (const float*)d_in[15];
    const float* fc_w     = (const float*)d_in[16];
    const float* fc_b     = (const float*)d_in[17];
    const float* res_w    = (const float*)d_in[18];
    const float* res_b    = (const float*)d_in[19];
    const float* res_alpha= (const float*)d_in[20];
    const float* ln_g     = (const float*)d_in[21];
    const float* ln_b     = (const float*)d_in[22];
    (void)in_sizes; (void)n_in; (void)out_size;

    int TB = (ws_size >= (size_t)500 * 1024 * 1024) ? 6 : 2;
    int CH = (TB == 6) ? N_ : 12500;

    char* ws = (char*)d_ws;
    size_t off = 0;
    auto alloc = [&](size_t bytes) -> void* {
        void* p = ws + off;
        off += (bytes + 255) & ~(size_t)255;
        return p;
    };
    int*   counts      = (int*)alloc((size_t)R_ * N_ * 4);
    int*   offsets     = (int*)alloc((size_t)R_ * (N_ + 1) * 4);
    int*   cursor      = (int*)alloc((size_t)R_ * N_ * 4);
    int*   srcs_sorted = (int*)alloc((size_t)R_ * E_ * 4);
    int*   lexcl       = (int*)alloc((size_t)R_ * N_ * 4);
    int*   csums       = (int*)alloc((size_t)R_ * 64 * 4);
    float* pe          = (float*)alloc(T_ * NH_ * 4);
    float* partials    = (float*)alloc((size_t)T_ * SEMW_BLOCKS * 2 * 4);
    float* beta2       = (float*)alloc(T_ * 2 * 4);
    float* Mu          = (float*)alloc(16384 * 4);
    float* Mwv         = (float*)alloc(16384 * 4);
    float* cbuf        = (float*)alloc(4 * 768 * 4);
    unsigned short* wt_gs0  = (unsigned short*)alloc(16384 * 2);
    unsigned short* wt_gs1  = (unsigned short*)alloc(16384 * 2);
    unsigned short* wt_gd0  = (unsigned short*)alloc(16384 * 2);
    unsigned short* wt_gd1  = (unsigned short*)alloc(16384 * 2);
    unsigned short* wt_sem  = (unsigned short*)alloc(16384 * 2);
    unsigned short* wt_res  = (unsigned short*)alloc(16384 * 2);
    unsigned short* wt_hh   = (unsigned short*)alloc(16384 * 2);
    unsigned short* wt_pu   = (unsigned short*)alloc(16384 * 2);
    unsigned short* wt_pwv  = (unsigned short*)alloc(16384 * 2);
    unsigned short* inter   = nullptr;
    if (TB != 6) inter = (unsigned short*)alloc((size_t)N_ * T_ * 128 * 2);        // TB=2 fallback
    size_t Rgat = (size_t)4 * TB * N_ * 128 * 2;
    size_t Rtmp = (size_t)4 * CH * 6 * 128 * 2;
    unsigned short* R0      = (unsigned short*)alloc(Rgat > Rtmp ? Rgat : Rtmp);

    unsigned short* hbuf = (unsigned short*)d_out;   // TB*N*256 bf16 <= 153.6 MB; overwritten afterwards

    // --- CSR + precomputes
    hipMemsetAsync(counts, 0, (size_t)R_ * N_ * 4, stream);
    hist_kernel<<<(R_ * E_ + 255) / 256, 256, 0, stream>>>(dst, counts);
    scan1_kernel<<<dim3(NCHUNK, R_), 1024, 0, stream>>>(counts, lexcl, csums);
    scan2_kernel<<<1, 128, 0, stream>>>(csums, offsets);
    scan3_kernel<<<dim3(NCHUNK, R_), 1024, 0, stream>>>(lexcl, csums, offsets, cursor);
    scatter_kernel<<<(R_ * E_ + 255) / 256, 256, 0, stream>>>(src, dst, cursor, srcs_sorted);
    pe_kernel<<<1, 128, 0, stream>>>(pe);
    CvtArgs ca;
    ca.s[0] = gat_wsrc;         ca.d[0] = wt_gs0;
    ca.s[1] = gat_wsrc + 16384; ca.d[1] = wt_gs1;
    ca.s[2] = gat_wdst;         ca.d[2] = wt_gd0;
    ca.s[3] = gat_wdst + 16384; ca.d[3] = wt_gd1;
    ca.s[4] = sem_w1;           ca.d[4] = wt_sem;
    ca.s[5] = res_w;            ca.d[5] = wt_res;
    cvt_wt_kernel<<<dim3(128, 6), 128, 0, stream>>>(ca);
    build_m_kernel<<<dim3(128, 2), 128, 0, stream>>>(qw, kw, vw, fc_w, Mu, Mwv);
    fold_w_kernel<<<dim3(128, 3), 128, 0, stream>>>(proj_w, Mu, Mwv, wt_hh, wt_pu, wt_pwv);
    fold_c_kernel<<<6, 128, 0, stream>>>(proj_b, pe, Mu, Mwv, res_b, cbuf);

    // --- GAT phase, batched over TB timesteps per group (A read directly from f32 x)
    size_t TBN = (size_t)TB * N_ * 128;
    for (int tg = 0; tg < T_ / TB; tg++) {
        int tbase = tg * TB;
        MArgs ga{};
        ga.A = (const void*)(x + (size_t)tbase * N_ * 128);
        ga.row0 = 0; ga.M = TB * N_;
        ga.W0 = wt_gs0; ga.C0 = R0;
        ga.W1 = wt_gd0; ga.C1 = R0 + TBN;
        ga.W2 = wt_gs1; ga.C2 = R0 + 2 * TBN;
        ga.W3 = wt_gd1; ga.C3 = R0 + 3 * TBN;
        mgemm_kernel<0><<<dim3((TB * N_ + 127) / 128, 1), 256, 0, stream>>>(ga);

        gat_edge_kernel<<<1024 * 2 * TB, 256, 0, stream>>>(R0, offsets, srcs_sorted,
                                                           gat_attn, gat_bias, hbuf, TB);

        semw_kernel<<<dim3(SEMW_BLOCKS, TB), 256, 0, stream>>>(hbuf, wt_sem, sem_b1, sem_w2,
                                                               partials + (size_t)tbase * SEMW_BLOCKS * 2);
        beta_kernel<<<TB, 512, 0, stream>>>(partials + (size_t)tbase * SEMW_BLOCKS * 2,
                                            beta2 + tbase * 2);
        if (TB != 6)
            hsem_kernel<<<dim3((N_ * 16 + 255) / 256, TB), 256, 0, stream>>>(hbuf, beta2 + tbase * 2,
                                                                             h_bias, inter, tbase);
    }

    // --- temporal attention + residual + LN (batched; overwrites d_out)
    for (int c = 0; c < N_ / CH; c++) {
        long n0 = (long)c * CH;
        long r0 = n0 * 6;
        int Mc = CH * 6;
        int nb = (Mc + 127) / 128;
        size_t MB = (size_t)Mc * 128;

        MArgs gt{};
        if (TB == 6) { gt.A = (const void*)hbuf; gt.mix = 1; }
        else         { gt.A = (const void*)(inter + (size_t)r0 * 128); gt.mix = 0; }
        gt.Axb = (const void*)x;
        gt.beta2 = beta2; gt.hb = h_bias;
        gt.row0 = r0; gt.M = Mc; gt.cb = cbuf;
        gt.W0 = wt_hh;  gt.C0 = R0;
        gt.W1 = wt_pu;  gt.C1 = R0 + MB;
        gt.W2 = wt_pwv; gt.C2 = R0 + 2 * MB;
        gt.W3 = wt_res; gt.C3 = R0 + 3 * MB;
        mgemm_kernel<3><<<dim3(nb, 1), 256, 0, stream>>>(gt);

        temporal_kernel<<<(CH + 3) / 4, 256, 0, stream>>>(R0, R0 + MB, R0 + 2 * MB, R0 + 3 * MB,
                                                          fc_b, res_alpha, ln_g, ln_b,
                                                          (float*)d_out, n0, CH);
    }
}

// Round 16
// 1215.280 us; speedup vs baseline: 1.0813x; 1.0813x over previous
//
#include <hip/hip_runtime.h>
#include <math.h>

#define T_  6
#define N_  50000
#define NH_ 128
#define R_  2
#define E_  800000
#define SEMW_BLOCKS ((2*N_ + 127)/128)   // 782
#define NCHUNK 49                         // ceil(N/1024)

typedef __attribute__((ext_vector_type(8))) short bf16x8;
typedef __attribute__((ext_vector_type(4))) float f32x4;

__device__ inline unsigned short f2b(float f) {
    union { float f; unsigned int u; } v; v.f = f;
    unsigned int u = v.u;
    unsigned int r = (u + 0x7FFFu + ((u >> 16) & 1u)) >> 16;
    return (unsigned short)r;
}
__device__ inline float b2f(unsigned short h) {
    union { unsigned int u; float f; } v; v.u = ((unsigned int)h) << 16;
    return v.f;
}
// async 16B global->LDS (linear LDS dest = wave-uniform base + lane*16)
__device__ inline void gload16(const void* g, void* l) {
    __builtin_amdgcn_global_load_lds((const __attribute__((address_space(1))) void*)g,
                                     (__attribute__((address_space(3))) void*)l, 16, 0, 0);
}

// ---------------------------------------------------------------- CSR build
__global__ void hist_kernel(const int* __restrict__ dst, int* __restrict__ counts) {
    int j = blockIdx.x * blockDim.x + threadIdx.x;
    if (j < R_ * E_) atomicAdd(&counts[(j / E_) * N_ + dst[j]], 1);
}

__global__ __launch_bounds__(1024) void scan1_kernel(const int* __restrict__ counts,
                                                     int* __restrict__ lexcl,
                                                     int* __restrict__ csums) {
    int r = blockIdx.y, c = blockIdx.x;
    int i = c * 1024 + threadIdx.x;
    int v = (i < N_) ? counts[r * N_ + i] : 0;
    __shared__ int sm[1024];
    sm[threadIdx.x] = v;
    __syncthreads();
    for (int off = 1; off < 1024; off <<= 1) {
        int t = 0;
        if (threadIdx.x >= off) t = sm[threadIdx.x - off];
        __syncthreads();
        sm[threadIdx.x] += t;
        __syncthreads();
    }
    if (i < N_) lexcl[r * N_ + i] = sm[threadIdx.x] - v;
    if (threadIdx.x == 1023) csums[r * 64 + c] = sm[1023];
}

__global__ void scan2_kernel(int* __restrict__ csums, int* __restrict__ offsets) {
    int r = threadIdx.x >> 6, l = threadIdx.x & 63;
    if (r < R_) {
        int v = (l < NCHUNK) ? csums[r * 64 + l] : 0;
        int s = v;
        for (int off = 1; off < 64; off <<= 1) {
            int t = __shfl_up(s, off);
            if (l >= off) s += t;
        }
        if (l < NCHUNK) csums[r * 64 + l] = s - v;
        if (l == NCHUNK - 1) offsets[r * (N_ + 1) + N_] = s;
    }
}

__global__ __launch_bounds__(1024) void scan3_kernel(const int* __restrict__ lexcl,
                                                     const int* __restrict__ csums,
                                                     int* __restrict__ offsets,
                                                     int* __restrict__ cursor) {
    int r = blockIdx.y;
    int i = blockIdx.x * 1024 + threadIdx.x;
    if (i < N_) {
        int o = lexcl[r * N_ + i] + csums[r * 64 + blockIdx.x];
        offsets[r * (N_ + 1) + i] = o;
        cursor[r * N_ + i] = o;
    }
}

__global__ void scatter_kernel(const int* __restrict__ src, const int* __restrict__ dst,
                               int* __restrict__ cursor, int* __restrict__ srcs_sorted) {
    int j = blockIdx.x * blockDim.x + threadIdx.x;
    if (j < R_ * E_) {
        int r = j / E_;
        int pos = atomicAdd(&cursor[r * N_ + dst[j]], 1);
        srcs_sorted[(size_t)r * E_ + pos] = src[j] << 8;   // prescaled byte offset (256 B/row)
    }
}

// ---------------------------------------------------------------- small precomputes
__global__ void pe_kernel(float* __restrict__ pe) {
    int c = threadIdx.x;
    int k = c & ~1;
    double div = exp((double)k * (-log(100000.0) / 128.0));
    for (int t = 0; t < T_; t++) {
        double pos = (double)(t + 1);
        double v = (c & 1) ? cos(pos * div) : sin(pos * div);
        pe[t * NH_ + c] = (float)v;
    }
}

struct CvtArgs {
    const float* s[6];
    unsigned short* d[6];
};
__global__ void cvt_wt_kernel(CvtArgs a) {
    int y = blockIdx.y, n = blockIdx.x, k = threadIdx.x;
    a.d[y][n * 128 + k] = f2b(a.s[y][k * 128 + n]);
}

__global__ void build_m_kernel(const float* __restrict__ qw, const float* __restrict__ kw,
                               const float* __restrict__ vw, const float* __restrict__ fcw,
                               float* __restrict__ Mu, float* __restrict__ Mwv) {
    int y = blockIdx.y, c = blockIdx.x, f = threadIdx.x;
    float s = 0.f;
    if (y == 0) {
        for (int d = 0; d < 128; d++) s += kw[f * 128 + d] * qw[c * 128 + d];
        Mu[c * 128 + f] = s;
    } else {
        for (int d = 0; d < 128; d++) s += vw[f * 128 + d] * fcw[d * 128 + c];
        Mwv[c * 128 + f] = s;
    }
}

__global__ void fold_w_kernel(const float* __restrict__ proj, const float* __restrict__ Mu,
                              const float* __restrict__ Mwv, unsigned short* __restrict__ wt_hh,
                              unsigned short* __restrict__ wt_pu, unsigned short* __restrict__ wt_pwv) {
    int y = blockIdx.y, c = blockIdx.x, k = threadIdx.x;
    if (y == 0) { wt_hh[c * 128 + k] = f2b(proj[k * 128 + c]); return; }
    const float* M = (y == 1) ? Mu : Mwv;
    float s = 0.f;
    for (int f = 0; f < 128; f++) s += proj[k * 128 + f] * M[c * 128 + f];
    ((y == 1) ? wt_pu : wt_pwv)[c * 128 + k] = f2b(s);
}

__global__ void fold_c_kernel(const float* __restrict__ proj_b, const float* __restrict__ pe,
                              const float* __restrict__ Mu, const float* __restrict__ Mwv,
                              const float* __restrict__ res_b, float* __restrict__ cbuf) {
    int t = blockIdx.x, c = threadIdx.x;
    cbuf[0 * 768 + t * 128 + c] = proj_b[c] + pe[t * 128 + c];
    float s1 = 0.f, s2 = 0.f;
    for (int f = 0; f < 128; f++) {
        float b = proj_b[f] + pe[t * 128 + f];
        s1 += b * Mu[c * 128 + f];
        s2 += b * Mwv[c * 128 + f];
    }
    cbuf[1 * 768 + t * 128 + c] = s1;
    cbuf[2 * 768 + t * 128 + c] = s2;
    cbuf[3 * 768 + t * 128 + c] = res_b[c];
}

// ---------------------------------------------------------------- MFMA GEMM, 4 fused outputs sharing the staged A-tile
struct MArgs {
    const void* A;               // EPI0: f32 rows; EPI3 mix=0: bf16 rows; EPI3 mix=1: hbuf [t][n][256]
    const void* Axb;             // EPI3 y3: x (f32) in [t][n] layout (mode-1 addressing)
    const unsigned short* W0; const unsigned short* W1;
    const unsigned short* W2; const unsigned short* W3;
    unsigned short* C0; unsigned short* C1; unsigned short* C2; unsigned short* C3;
    const float* cb;             // [4][6][128] (EPI 3)
    const float* beta2;          // [6][2] (mix)
    const float* hb;             // h_bias[128] (mix)
    long row0;
    int  M;
    int  mix;                    // EPI3: 1 = inline beta-mix from hbuf
};

// EPI: 0 = bf16 out, A is f32 (inline convert); 3 = + cb[y][t6][col], y3 reads f32 Axb
template <int EPI>
__global__ __launch_bounds__(256) void mgemm_kernel(MArgs g) {
    __shared__ __align__(16) char As[128 * 256];
    __shared__ __align__(16) char Bs[128 * 256];
    int tid = threadIdx.x;
    int lane = tid & 63;
    int wbase = tid & ~63;               // wave-uniform
    int brow0 = blockIdx.x * 128;
    const unsigned short* Ws[4] = {g.W0, g.W1, g.W2, g.W3};
    unsigned short* Cs[4] = {g.C0, g.C1, g.C2, g.C3};

    auto stageAsync = [&](const char* Sbase, char* L, bool clampRows) {
        int Mm1 = g.M - 1;
#pragma unroll
        for (int i = 0; i < 8; i++) {
            int c0 = wbase + i * 256;
            int cl = c0 + lane;
            int row = cl >> 4;
            int sb = ((cl & 15) << 4) ^ ((row & 7) << 4);
            long srow = clampRows ? (long)min(brow0 + row, Mm1) : (long)row;
            gload16(Sbase + srow * 256 + sb, L + (size_t)c0 * 16);
        }
    };
    auto stageA_f32 = [&](const float* Abase, bool m1) {
#pragma unroll
        for (int i = 0; i < 8; i++) {
            int c = tid + i * 256;
            int row = c >> 4;
            int cb = (c & 15) << 4;
            int scb = cb ^ ((row & 7) << 4);
            int grow = brow0 + row;
            uint4 av = make_uint4(0u, 0u, 0u, 0u);
            if (grow < g.M) {
                long ar;
                if (!m1) ar = grow;
                else { long gg = g.row0 + grow; long n = gg / 6, t = gg - n * 6; ar = t * (long)N_ + n; }
                const float* Af = Abase + ar * 128 + (cb >> 1);
                float4 x0 = *(const float4*)Af;
                float4 x1 = *(const float4*)(Af + 4);
                union { unsigned short s[8]; uint4 u; } o;
                o.s[0] = f2b(x0.x); o.s[1] = f2b(x0.y); o.s[2] = f2b(x0.z); o.s[3] = f2b(x0.w);
                o.s[4] = f2b(x1.x); o.s[5] = f2b(x1.y); o.s[6] = f2b(x1.z); o.s[7] = f2b(x1.w);
                av = o.u;
            }
            *(uint4*)(As + row * 256 + scb) = av;
        }
    };
    // EPI3 mix=1: A row g -> n=g/6, t=g%6; z = relu(relu(b0*h0+b1*h1)+h_bias)
    auto stageA_mix = [&](const unsigned short* H) {
#pragma unroll
        for (int i = 0; i < 8; i++) {
            int c = tid + i * 256;
            int row = c >> 4;
            int cb = (c & 15) << 4;
            int scb = cb ^ ((row & 7) << 4);
            int grow = brow0 + row;
            uint4 av = make_uint4(0u, 0u, 0u, 0u);
            if (grow < g.M) {
                long gg = g.row0 + grow;
                long n = gg / 6, t = gg - n * 6;
                const unsigned short* h = H + t * (size_t)N_ * 256 + n * 256 + (cb >> 1);
                uint4 x0 = *(const uint4*)h;
                uint4 x1 = *(const uint4*)(h + 128);
                float b0 = g.beta2[2 * t], b1 = g.beta2[2 * t + 1];
                const unsigned int* p0 = (const unsigned int*)&x0;
                const unsigned int* p1 = (const unsigned int*)&x1;
                int col0 = cb >> 1;
                union { unsigned short s[8]; uint4 u; } o;
#pragma unroll
                for (int j = 0; j < 8; j++) {
                    unsigned short s0 = (j & 1) ? (unsigned short)(p0[j >> 1] >> 16) : (unsigned short)p0[j >> 1];
                    unsigned short s1 = (j & 1) ? (unsigned short)(p1[j >> 1] >> 16) : (unsigned short)p1[j >> 1];
                    float z = fmaxf(fmaxf(b0 * b2f(s0) + b1 * b2f(s1), 0.f) + g.hb[col0 + j], 0.f);
                    o.s[j] = f2b(z);
                }
                av = o.u;
            }
            *(uint4*)(As + row * 256 + scb) = av;
        }
    };

    int w = tid >> 6, l = tid & 63;
    int l15 = l & 15, lg = l >> 4;

    if (EPI == 0) stageA_f32((const float*)g.A, false);
    else if (g.mix) stageA_mix((const unsigned short*)g.A);
    else stageAsync((const char*)g.A, As, true);

    for (int y = 0; y < 4; y++) {
        if (y > 0) __syncthreads();
        if (EPI == 3 && y == 3) stageA_f32((const float*)g.Axb, true);
        stageAsync((const char*)Ws[y], Bs, false);
        __syncthreads();

        f32x4 acc[2][8];
#pragma unroll
        for (int a = 0; a < 2; a++)
#pragma unroll
            for (int b = 0; b < 8; b++) acc[a][b] = (f32x4)(0.f);
#pragma unroll
        for (int ks = 0; ks < 4; ks++) {
            bf16x8 bf[8];
#pragma unroll
            for (int nt = 0; nt < 8; nt++) {
                int rn = nt * 16 + l15;
                int cbyte = (ks * 64 + lg * 16) ^ ((rn & 7) << 4);
                bf[nt] = *(const bf16x8*)(Bs + rn * 256 + cbyte);
            }
#pragma unroll
            for (int mt = 0; mt < 2; mt++) {
                int rm = w * 32 + mt * 16 + l15;
                int cbyte = (ks * 64 + lg * 16) ^ ((rm & 7) << 4);
                bf16x8 af = *(const bf16x8*)(As + rm * 256 + cbyte);
#pragma unroll
                for (int nt = 0; nt < 8; nt++)
                    acc[mt][nt] = __builtin_amdgcn_mfma_f32_16x16x32_bf16(af, bf[nt], acc[mt][nt], 0, 0, 0);
            }
        }
        unsigned short* C = Cs[y];
#pragma unroll
        for (int mt = 0; mt < 2; mt++) {
#pragma unroll
            for (int r = 0; r < 4; r++) {
                int row = w * 32 + mt * 16 + lg * 4 + r;
                int grow = brow0 + row;
                if (grow >= g.M) continue;
                long t6 = 0;
                if (EPI == 3) t6 = (g.row0 + grow) % 6;
#pragma unroll
                for (int nt = 0; nt < 8; nt++) {
                    int col = nt * 16 + l15;
                    float v = acc[mt][nt][r];
                    if (EPI == 3) v += g.cb[y * 768 + t6 * 128 + col];
                    C[(size_t)grow * 128 + col] = f2b(v);
                }
            }
        }
    }
}

// ---------------------------------------------------------------- semantic w partials (batched over t via blockIdx.y)
__global__ __launch_bounds__(256) void semw_kernel(const unsigned short* __restrict__ Abase,
                                                   const unsigned short* __restrict__ Wt,
                                                   const float* __restrict__ b1,
                                                   const float* __restrict__ w2,
                                                   float* __restrict__ partials) {
    __shared__ __align__(16) char As[128 * 256];
    __shared__ __align__(16) char Bs[128 * 256];
    __shared__ float bs[2];
    int tid = threadIdx.x;
    if (tid < 2) bs[tid] = 0.f;
    int lane = tid & 63;
    int wbase = tid & ~63;
    int tl = blockIdx.y;
    const char* A = (const char*)(Abase + (size_t)tl * N_ * 256);
    const int M = 2 * N_;
    int brow0 = blockIdx.x * 128;
#pragma unroll
    for (int i = 0; i < 8; i++) {
        int c0 = wbase + i * 256;
        int cl = c0 + lane;
        int row = cl >> 4;
        int sb = ((cl & 15) << 4) ^ ((row & 7) << 4);
        gload16((const char*)Wt + (long)row * 256 + sb, Bs + (size_t)c0 * 16);
        long srow = min(brow0 + row, M - 1);
        gload16(A + srow * 256 + sb, As + (size_t)c0 * 16);
    }
    __syncthreads();
    int w = tid >> 6, l = tid & 63;
    int l15 = l & 15, lg = l >> 4;
    f32x4 acc[2][8];
#pragma unroll
    for (int a = 0; a < 2; a++)
#pragma unroll
        for (int b = 0; b < 8; b++) acc[a][b] = (f32x4)(0.f);
#pragma unroll
    for (int ks = 0; ks < 4; ks++) {
        bf16x8 bf[8];
#pragma unroll
        for (int nt = 0; nt < 8; nt++) {
            int rn = nt * 16 + l15;
            int cbyte = (ks * 64 + lg * 16) ^ ((rn & 7) << 4);
            bf[nt] = *(const bf16x8*)(Bs + rn * 256 + cbyte);
        }
#pragma unroll
        for (int mt = 0; mt < 2; mt++) {
            int rm = w * 32 + mt * 16 + l15;
            int cbyte = (ks * 64 + lg * 16) ^ ((rm & 7) << 4);
            bf16x8 af = *(const bf16x8*)(As + rm * 256 + cbyte);
#pragma unroll
            for (int nt = 0; nt < 8; nt++)
                acc[mt][nt] = __builtin_amdgcn_mfma_f32_16x16x32_bf16(af, bf[nt], acc[mt][nt], 0, 0, 0);
        }
    }
#pragma unroll
    for (int mt = 0; mt < 2; mt++) {
#pragma unroll
        for (int r = 0; r < 4; r++) {
            int row = w * 32 + mt * 16 + lg * 4 + r;
            int grow = brow0 + row;
            float s = 0.f;
#pragma unroll
            for (int nt = 0; nt < 8; nt++) {
                int col = nt * 16 + l15;
                s += tanhf(acc[mt][nt][r] + b1[col]) * w2[col];
            }
#pragma unroll
            for (int mask = 1; mask <= 8; mask <<= 1) s += __shfl_xor(s, mask);
            if (l15 == 0 && grow < M) atomicAdd(&bs[grow & 1], s);
        }
    }
    __syncthreads();
    if (tid < 2) partials[((size_t)tl * SEMW_BLOCKS + blockIdx.x) * 2 + tid] = bs[tid];
}

__global__ __launch_bounds__(512) void beta_kernel(const float* __restrict__ partials,
                                                   float* __restrict__ beta2) {
    int t = blockIdx.x;
    const float* p = partials + (size_t)t * SEMW_BLOCKS * 2;
    float s0 = 0.f, s1 = 0.f;
    for (int i = threadIdx.x; i < SEMW_BLOCKS; i += 512) { s0 += p[i * 2]; s1 += p[i * 2 + 1]; }
#pragma unroll
    for (int mask = 1; mask <= 32; mask <<= 1) { s0 += __shfl_xor(s0, mask); s1 += __shfl_xor(s1, mask); }
    __shared__ float w0[8], w1[8];
    int w = threadIdx.x >> 6;
    if ((threadIdx.x & 63) == 0) { w0[w] = s0; w1[w] = s1; }
    __syncthreads();
    if (threadIdx.x == 0) {
        float t0 = 0.f, t1 = 0.f;
        for (int i = 0; i < 8; i++) { t0 += w0[i]; t1 += w1[i]; }
        float m0 = t0 / (float)N_, m1 = t1 / (float)N_;
        float mx = fmaxf(m0, m1);
        float e0 = __expf(m0 - mx), e1 = __expf(m1 - mx);
        float inv = 1.f / (e0 + e1);
        beta2[t * 2] = e0 * inv; beta2[t * 2 + 1] = e1 * inv;
    }
}

// ---------------------------------------------------------------- GAT edge aggregation: 4 nodes/wave, 16 lanes/node, 8 ch/lane
__global__ __launch_bounds__(256) void gat_edge_kernel(const unsigned short* __restrict__ R0,
                                                       const int* __restrict__ offsets,
                                                       const int* __restrict__ srcs_sorted,
                                                       const float* __restrict__ gat_attn,
                                                       const float* __restrict__ gat_bias,
                                                       unsigned short* __restrict__ hbuf, int TB) {
    int y = blockIdx.x >> 10;              // slice (slow dimension)
    int bid = blockIdx.x & 1023;
    int r = y & 1, tl = y >> 1;
    const char* fsb = (const char*)(R0 + ((size_t)(2 * r) * TB + tl) * N_ * 128);
    const unsigned short* fd = R0 + ((size_t)(2 * r + 1) * TB + tl) * N_ * 128;
    unsigned short* hout = hbuf + (size_t)tl * N_ * 256;
    const int* offs = offsets + r * (N_ + 1);
    const int* srcs = srcs_sorted + (size_t)r * E_;
    int lane = threadIdx.x & 63;
    int q = lane >> 4, l16 = lane & 15;
    int c0 = l16 * 8;
    const char* fsc = fsb + c0 * 2;
    int wid = (bid * blockDim.x + threadIdx.x) >> 6;
    int nw = (1024 * blockDim.x) >> 6;
    float4 a0 = *(const float4*)(gat_attn + r * 128 + c0);
    float4 a1 = *(const float4*)(gat_attn + r * 128 + c0 + 4);
    float av[8] = {a0.x, a0.y, a0.z, a0.w, a1.x, a1.y, a1.z, a1.w};
    float4 bb0 = *(const float4*)(gat_bias + r * 128 + c0);
    float4 bb1 = *(const float4*)(gat_bias + r * 128 + c0 + 4);
    float bv[8] = {bb0.x, bb0.y, bb0.z, bb0.w, bb1.x, bb1.y, bb1.z, bb1.w};

    for (int gidx = wid; gidx < N_ / 4; gidx += nw) {
        int n = gidx * 4 + q;
        uint4 fdp = *(const uint4*)(fd + (size_t)n * 128 + c0);
        const unsigned int* fdu = (const unsigned int*)&fdp;
        float fdv[8];
#pragma unroll
        for (int j = 0; j < 8; j++)
            fdv[j] = (j & 1) ? b2f((unsigned short)(fdu[j >> 1] >> 16)) : b2f((unsigned short)fdu[j >> 1]);
        int e0 = offs[n], e1 = offs[n + 1];
        int deg = e1 - e0;
        int m = deg;
        m = max(m, __shfl_xor(m, 16));
        m = max(m, __shfl_xor(m, 32));
        float den = 0.f;
        float acc[8];
#pragma unroll
        for (int j = 0; j < 8; j++) acc[j] = 0.f;

        uint4 fp = make_uint4(0u, 0u, 0u, 0u);
        if (deg > 0) fp = *(const uint4*)(fsc + srcs[e0]);
        for (int i = 0; i < m; i++) {
            uint4 nxt = make_uint4(0u, 0u, 0u, 0u);
            if (i + 1 < deg) nxt = *(const uint4*)(fsc + srcs[e0 + i + 1]);
            const unsigned int* fu = (const unsigned int*)&fp;
            float f[8];
            float vlin = 0.f, vabs = 0.f;
#pragma unroll
            for (int j = 0; j < 8; j++) {
                f[j] = (j & 1) ? b2f((unsigned short)(fu[j >> 1] >> 16)) : b2f((unsigned short)fu[j >> 1]);
                float t = f[j] + fdv[j];
                vlin = fmaf(av[j], t, vlin);
                vabs = fmaf(av[j], fabsf(t), vabs);     // abs = free input modifier
            }
            float v = fmaf(0.4f, vabs, 0.6f * vlin);    // combine BEFORE reduce (linear)
            v += __int_as_float(__builtin_amdgcn_ds_swizzle(__float_as_int(v), 0x041F));
            v += __int_as_float(__builtin_amdgcn_ds_swizzle(__float_as_int(v), 0x081F));
            float p = (i < deg) ? __expf(v) : 0.f;      // logits O(1): no max subtraction needed
            den += p;
#pragma unroll
            for (int j = 0; j < 8; j++) acc[j] = fmaf(p, f[j], acc[j]);
            fp = nxt;
        }
        float inv = (deg > 0) ? 1.f / den : 0.f;
        union { unsigned short s[8]; uint4 u; } o;
#pragma unroll
        for (int j = 0; j < 8; j++) o.s[j] = f2b(fmaf(acc[j], inv, bv[j]));
        *(uint4*)(hout + (size_t)(n * 2 + r) * 128 + c0) = o.u;
    }
}

// ---------------------------------------------------------------- hsem (TB=2 fallback only)
__global__ void hsem_kernel(const unsigned short* __restrict__ hbuf, const float* __restrict__ beta2,
                            const float* __restrict__ h_bias, unsigned short* __restrict__ inter,
                            int tbase) {
    int idx = blockIdx.x * blockDim.x + threadIdx.x;
    if (idx >= N_ * 16) return;
    int tl = blockIdx.y;
    int t = tbase + tl;
    const unsigned short* h = hbuf + (size_t)tl * N_ * 256;
    int n = idx >> 4, c8 = (idx & 15) * 8;
    float b0 = beta2[tl * 2], b1 = beta2[tl * 2 + 1];
    uint4 x0 = *(const uint4*)(h + (size_t)n * 256 + c8);
    uint4 x1 = *(const uint4*)(h + (size_t)n * 256 + 128 + c8);
    const unsigned int* p0 = (const unsigned int*)&x0;
    const unsigned int* p1 = (const unsigned int*)&x1;
    float4 hb0 = *(const float4*)(h_bias + c8);
    float4 hb1 = *(const float4*)(h_bias + c8 + 4);
    float hbv[8] = {hb0.x, hb0.y, hb0.z, hb0.w, hb1.x, hb1.y, hb1.z, hb1.w};
    union { unsigned short s[8]; uint4 u; } o;
#pragma unroll
    for (int i = 0; i < 8; i++) {
        unsigned short s0 = (i & 1) ? (unsigned short)(p0[i >> 1] >> 16) : (unsigned short)p0[i >> 1];
        unsigned short s1 = (i & 1) ? (unsigned short)(p1[i >> 1] >> 16) : (unsigned short)p1[i >> 1];
        float z = fmaxf(fmaxf(b0 * b2f(s0) + b1 * b2f(s1), 0.f) + hbv[i], 0.f);
        o.s[i] = f2b(z);
    }
    *(uint4*)(inter + ((size_t)n * 6 + t) * 128 + c8) = o.u;
}

// ---------------------------------------------------------------- temporal attention + gated residual + LN
__global__ __launch_bounds__(256) void temporal_kernel(const unsigned short* __restrict__ hh,
                                                       const unsigned short* __restrict__ uu,
                                                       const unsigned short* __restrict__ wvv,
                                                       const unsigned short* __restrict__ rv,
                                                       const float* __restrict__ fc_b,
                                                       const float* __restrict__ res_alpha,
                                                       const float* __restrict__ ln_g,
                                                       const float* __restrict__ ln_b,
                                                       float* __restrict__ out, long n0, int nNodes) {
    int lane = threadIdx.x & 63;
    int wid = (blockIdx.x * blockDim.x + threadIdx.x) >> 6;
    if (wid >= nNodes) return;
    long n = n0 + wid;
    size_t base = (size_t)wid * 6 * 128 + 2 * lane;
    float h2[6][2], u2[6][2], wv2[6][2], rv2[6][2];
#pragma unroll
    for (int t = 0; t < 6; t++) {
        unsigned int hp = *(const unsigned int*)(hh + base + t * 128);
        h2[t][0] = b2f((unsigned short)hp); h2[t][1] = b2f((unsigned short)(hp >> 16));
        unsigned int up = *(const unsigned int*)(uu + base + t * 128);
        u2[t][0] = b2f((unsigned short)up); u2[t][1] = b2f((unsigned short)(up >> 16));
        unsigned int wp = *(const unsigned int*)(wvv + base + t * 128);
        wv2[t][0] = b2f((unsigned short)wp); wv2[t][1] = b2f((unsigned short)(wp >> 16));
        unsigned int rp = *(const unsigned int*)(rv + base + t * 128);
        rv2[t][0] = b2f((unsigned short)rp); rv2[t][1] = b2f((unsigned short)(rp >> 16));
    }
    float sc[6][6];
#pragma unroll
    for (int t = 0; t < 6; t++)
#pragma unroll
        for (int s = 0; s < 6; s++)
            sc[t][s] = h2[t][0] * u2[s][0] + h2[t][1] * u2[s][1];
#pragma unroll
    for (int mask = 1; mask <= 32; mask <<= 1)
#pragma unroll
        for (int t = 0; t < 6; t++)
#pragma unroll
            for (int s = 0; s < 6; s++)
                sc[t][s] += __shfl_xor(sc[t][s], mask);

    float a = 1.f / (1.f + __expf(-res_alpha[0]));
    float2 fb = ((const float2*)fc_b)[lane];
    float2 lg = ((const float2*)ln_g)[lane];
    float2 lb = ((const float2*)ln_b)[lane];
#pragma unroll
    for (int t = 0; t < 6; t++) {
        float mx = sc[t][0];
#pragma unroll
        for (int s = 1; s < 6; s++) mx = fmaxf(mx, sc[t][s]);
        float p[6]; float den = 0.f;
#pragma unroll
        for (int s = 0; s < 6; s++) { p[s] = __expf(sc[t][s] - mx); den += p[s]; }
        float inv = 1.f / den;
        float ox = 0.f, oy = 0.f;
#pragma unroll
        for (int s = 0; s < 6; s++) { ox += p[s] * wv2[s][0]; oy += p[s] * wv2[s][1]; }
        ox = fmaxf(ox * inv + fb.x, 0.f);
        oy = fmaxf(oy * inv + fb.y, 0.f);
        ox = ox * a + rv2[t][0] * (1.f - a);
        oy = oy * a + rv2[t][1] * (1.f - a);
        float s1 = ox + oy, s2 = ox * ox + oy * oy;
#pragma unroll
        for (int mask = 1; mask <= 32; mask <<= 1) {
            s1 += __shfl_xor(s1, mask);
            s2 += __shfl_xor(s2, mask);
        }
        float mu = s1 * (1.f / 128.f);
        float var = s2 * (1.f / 128.f) - mu * mu;
        float rs = rsqrtf(var + 1e-5f);
        float2 o;
        o.x = (ox - mu) * rs * lg.x + lb.x;
        o.y = (oy - mu) * rs * lg.y + lb.y;
        ((float2*)(out + ((size_t)t * N_ + n) * 128))[lane] = o;
    }
}

// ---------------------------------------------------------------- launch
extern "C" void kernel_launch(void* const* d_in, const int* in_sizes, int n_in,
                              void* d_out, int out_size, void* d_ws, size_t ws_size,
                              hipStream_t stream) {
    const float* x        = (const float*)d_in[0];
    const int*   src      = (const int*)d_in[1];
    const int*   dst      = (const int*)d_in[2];
    const float* gat_wsrc = (const float*)d_in[3];
    const float* gat_wdst = (const float*)d_in[4];
    const float* gat_attn = (const float*)d_in[5];
    const float* gat_bias = (const float*)d_in[6];
    const float* h_bias   = (const float*)d_in[7];
    const float* sem_w1   = (const float*)d_in[8];
    const float* sem_b1   = (const float*)d_in[9];
    const float* sem_w2   = (const float*)d_in[10];
    const float* proj_w   = (const float*)d_in[11];
    const float* proj_b   = (const float*)d_in[12];
    const float* qw       = (const float*)d_in[13];
    const float* kw       = (const float*)d_in[14];
    const float* vw       = (const float*)d_in[15];
    const float* fc_w     = (const float*)d_in[16];
    const float* fc_b     = (const float*)d_in[17];
    const float* res_w    = (const float*)d_in[18];
    const float* res_b    = (const float*)d_in[19];
    const float* res_alpha= (const float*)d_in[20];
    const float* ln_g     = (const float*)d_in[21];
    const float* ln_b     = (const float*)d_in[22];
    (void)in_sizes; (void)n_in; (void)out_size;

    int TB = (ws_size >= (size_t)500 * 1024 * 1024) ? 6 : 2;
    int CH = (TB == 6) ? N_ : 12500;

    char* ws = (char*)d_ws;
    size_t off = 0;
    auto alloc = [&](size_t bytes) -> void* {
        void* p = ws + off;
        off += (bytes + 255) & ~(size_t)255;
        return p;
    };
    int*   counts      = (int*)alloc((size_t)R_ * N_ * 4);
    int*   offsets     = (int*)alloc((size_t)R_ * (N_ + 1) * 4);
    int*   cursor      = (int*)alloc((size_t)R_ * N_ * 4);
    int*   srcs_sorted = (int*)alloc((size_t)R_ * E_ * 4);
    int*   lexcl       = (int*)alloc((size_t)R_ * N_ * 4);
    int*   csums       = (int*)alloc((size_t)R_ * 64 * 4);
    float* pe          = (float*)alloc(T_ * NH_ * 4);
    float* partials    = (float*)alloc((size_t)T_ * SEMW_BLOCKS * 2 * 4);
    float* beta2       = (float*)alloc(T_ * 2 * 4);
    float* Mu          = (float*)alloc(16384 * 4);
    float* Mwv         = (float*)alloc(16384 * 4);
    float* cbuf        = (float*)alloc(4 * 768 * 4);
    unsigned short* wt_gs0  = (unsigned short*)alloc(16384 * 2);
    unsigned short* wt_gs1  = (unsigned short*)alloc(16384 * 2);
    unsigned short* wt_gd0  = (unsigned short*)alloc(16384 * 2);
    unsigned short* wt_gd1  = (unsigned short*)alloc(16384 * 2);
    unsigned short* wt_sem  = (unsigned short*)alloc(16384 * 2);
    unsigned short* wt_res  = (unsigned short*)alloc(16384 * 2);
    unsigned short* wt_hh   = (unsigned short*)alloc(16384 * 2);
    unsigned short* wt_pu   = (unsigned short*)alloc(16384 * 2);
    unsigned short* wt_pwv  = (unsigned short*)alloc(16384 * 2);
    unsigned short* inter   = nullptr;
    if (TB != 6) inter = (unsigned short*)alloc((size_t)N_ * T_ * 128 * 2);        // TB=2 fallback
    size_t Rgat = (size_t)4 * TB * N_ * 128 * 2;
    size_t Rtmp = (size_t)4 * CH * 6 * 128 * 2;
    unsigned short* R0      = (unsigned short*)alloc(Rgat > Rtmp ? Rgat : Rtmp);

    unsigned short* hbuf = (unsigned short*)d_out;   // TB*N*256 bf16 <= 153.6 MB; overwritten afterwards

    // --- CSR + precomputes
    hipMemsetAsync(counts, 0, (size_t)R_ * N_ * 4, stream);
    hist_kernel<<<(R_ * E_ + 255) / 256, 256, 0, stream>>>(dst, counts);
    scan1_kernel<<<dim3(NCHUNK, R_), 1024, 0, stream>>>(counts, lexcl, csums);
    scan2_kernel<<<1, 128, 0, stream>>>(csums, offsets);
    scan3_kernel<<<dim3(NCHUNK, R_), 1024, 0, stream>>>(lexcl, csums, offsets, cursor);
    scatter_kernel<<<(R_ * E_ + 255) / 256, 256, 0, stream>>>(src, dst, cursor, srcs_sorted);
    pe_kernel<<<1, 128, 0, stream>>>(pe);
    CvtArgs ca;
    ca.s[0] = gat_wsrc;         ca.d[0] = wt_gs0;
    ca.s[1] = gat_wsrc + 16384; ca.d[1] = wt_gs1;
    ca.s[2] = gat_wdst;         ca.d[2] = wt_gd0;
    ca.s[3] = gat_wdst + 16384; ca.d[3] = wt_gd1;
    ca.s[4] = sem_w1;           ca.d[4] = wt_sem;
    ca.s[5] = res_w;            ca.d[5] = wt_res;
    cvt_wt_kernel<<<dim3(128, 6), 128, 0, stream>>>(ca);
    build_m_kernel<<<dim3(128, 2), 128, 0, stream>>>(qw, kw, vw, fc_w, Mu, Mwv);
    fold_w_kernel<<<dim3(128, 3), 128, 0, stream>>>(proj_w, Mu, Mwv, wt_hh, wt_pu, wt_pwv);
    fold_c_kernel<<<6, 128, 0, stream>>>(proj_b, pe, Mu, Mwv, res_b, cbuf);

    // --- GAT phase, batched over TB timesteps per group (A read directly from f32 x)
    size_t TBN = (size_t)TB * N_ * 128;
    for (int tg = 0; tg < T_ / TB; tg++) {
        int tbase = tg * TB;
        MArgs ga{};
        ga.A = (const void*)(x + (size_t)tbase * N_ * 128);
        ga.row0 = 0; ga.M = TB * N_;
        ga.W0 = wt_gs0; ga.C0 = R0;
        ga.W1 = wt_gd0; ga.C1 = R0 + TBN;
        ga.W2 = wt_gs1; ga.C2 = R0 + 2 * TBN;
        ga.W3 = wt_gd1; ga.C3 = R0 + 3 * TBN;
        mgemm_kernel<0><<<dim3((TB * N_ + 127) / 128, 1), 256, 0, stream>>>(ga);

        gat_edge_kernel<<<1024 * 2 * TB, 256, 0, stream>>>(R0, offsets, srcs_sorted,
                                                           gat_attn, gat_bias, hbuf, TB);

        semw_kernel<<<dim3(SEMW_BLOCKS, TB), 256, 0, stream>>>(hbuf, wt_sem, sem_b1, sem_w2,
                                                               partials + (size_t)tbase * SEMW_BLOCKS * 2);
        beta_kernel<<<TB, 512, 0, stream>>>(partials + (size_t)tbase * SEMW_BLOCKS * 2,
                                            beta2 + tbase * 2);
        if (TB != 6)
            hsem_kernel<<<dim3((N_ * 16 + 255) / 256, TB), 256, 0, stream>>>(hbuf, beta2 + tbase * 2,
                                                                             h_bias, inter, tbase);
    }

    // --- temporal attention + residual + LN (batched; overwrites d_out)
    for (int c = 0; c < N_ / CH; c++) {
        long n0 = (long)c * CH;
        long r0 = n0 * 6;
        int Mc = CH * 6;
        int nb = (Mc + 127) / 128;
        size_t MB = (size_t)Mc * 128;

        MArgs gt{};
        if (TB == 6) { gt.A = (const void*)hbuf; gt.mix = 1; }
        else         { gt.A = (const void*)(inter + (size_t)r0 * 128); gt.mix = 0; }
        gt.Axb = (const void*)x;
        gt.beta2 = beta2; gt.hb = h_bias;
        gt.row0 = r0; gt.M = Mc; gt.cb = cbuf;
        gt.W0 = wt_hh;  gt.C0 = R0;
        gt.W1 = wt_pu;  gt.C1 = R0 + MB;
        gt.W2 = wt_pwv; gt.C2 = R0 + 2 * MB;
        gt.W3 = wt_res; gt.C3 = R0 + 3 * MB;
        mgemm_kernel<3><<<dim3(nb, 1), 256, 0, stream>>>(gt);

        temporal_kernel<<<(CH + 3) / 4, 256, 0, stream>>>(R0, R0 + MB, R0 + 2 * MB, R0 + 3 * MB,
                                                          fc_b, res_alpha, ln_g, ln_b,
                                                          (float*)d_out, n0, CH);
    }
}